// Round 1
// baseline (348.681 us; speedup 1.0000x reference)
//
#include <hip/hip_runtime.h>

typedef __attribute__((ext_vector_type(8))) short short8;
typedef __attribute__((ext_vector_type(4))) float f32x4;
typedef unsigned short u16;
typedef unsigned int u32;

#define TAU_F 0.3f

__device__ __forceinline__ u16 f2bf(float f){
  u32 u = __float_as_uint(f);
  u32 r = u + 0x7FFFu + ((u >> 16) & 1u);
  return (u16)(r >> 16);
}
__device__ __forceinline__ float bf2f(u16 v){
  return __uint_as_float(((u32)v) << 16);
}

typedef __attribute__((address_space(1))) const u32 glb_u32;
typedef __attribute__((address_space(3))) u32 lds_u32;
__device__ __forceinline__ void async_lds16(const void* g, void* l){
  __builtin_amdgcn_global_load_lds((glb_u32*)g, (lds_u32*)l, 16, 0, 0);
}

// ---------------- generic bf16 NT GEMM, 128x128 tile, BK=32 (m97 structure) ----
// MODE 0: adj-byte epilogue (sim > TAU && valid_i && valid_j)
// MODE 1: gT store  (out[(b*128+c)*1024 + l] = bf16(acc)), b=row>>10, l=row&1023
// MODE 2: tanh(acc + bvec[col]) -> bf16, ldc=512
template<int MODE>
__global__ __launch_bounds__(256)
void gemm_nt(const u16* __restrict__ A, const u16* __restrict__ B,
             int lda, int ldb, int K, long sA, long sB,
             void* __restrict__ outp,
             const int* __restrict__ valid,
             const float* __restrict__ bvec)
{
  __shared__ u16 lA[128*32];
  __shared__ u16 lB[128*32];
  const int t = threadIdx.x;
  const int w = t >> 6, lane = t & 63;
  const int bz = blockIdx.z;
  const int i0 = blockIdx.y * 128, n0 = blockIdx.x * 128;
  const u16* Ab = A + (long)bz * sA;
  const u16* Bb = B + (long)bz * sB;
  const int wr = w >> 1, wc = w & 1;
  const int srow = t >> 2;         // 0..63 staging row
  const int scol = (t & 3) * 8;    // staging col (elems)
  const int rA = lane & 15, kb = (lane >> 4) * 8;
  f32x4 acc[4][4] = {};

  for (int kt = 0; kt < K; kt += 32) {
    __syncthreads();
    async_lds16(Ab + (long)(i0 +      srow) * lda + kt + scol, &lA[       w*512]);
    async_lds16(Ab + (long)(i0 + 64 + srow) * lda + kt + scol, &lA[2048 + w*512]);
    async_lds16(Bb + (long)(n0 +      srow) * ldb + kt + scol, &lB[       w*512]);
    async_lds16(Bb + (long)(n0 + 64 + srow) * ldb + kt + scol, &lB[2048 + w*512]);
    __syncthreads();
    short8 af[4], bfr[4];
#pragma unroll
    for (int m = 0; m < 4; m++)
      af[m] = *(const short8*)&lA[(wr*64 + m*16 + rA)*32 + kb];
#pragma unroll
    for (int n = 0; n < 4; n++)
      bfr[n] = *(const short8*)&lB[(wc*64 + n*16 + rA)*32 + kb];
#pragma unroll
    for (int m = 0; m < 4; m++)
#pragma unroll
      for (int n = 0; n < 4; n++)
        acc[m][n] = __builtin_amdgcn_mfma_f32_16x16x32_bf16(af[m], bfr[n], acc[m][n], 0, 0, 0);
  }

#pragma unroll
  for (int m = 0; m < 4; m++) {
    const int gi0 = i0 + wr*64 + m*16 + ((lane >> 4) << 2);
#pragma unroll
    for (int n = 0; n < 4; n++) {
      const int gj = n0 + wc*64 + n*16 + (lane & 15);
#pragma unroll
      for (int r = 0; r < 4; r++) {
        const int gi = gi0 + r;
        const float c = acc[m][n][r];
        if (MODE == 0) {
          unsigned char e = (c > TAU_F && valid[(bz<<10) + gi] && valid[(bz<<10) + gj]) ? 1 : 0;
          ((unsigned char*)outp)[((long)bz << 20) + ((long)gi << 10) + gj] = e;
        } else if (MODE == 1) {
          const int b = gi >> 10, l = gi & 1023;
          ((u16*)outp)[(((long)(b*128 + gj)) << 10) + l] = f2bf(c);
        } else {
          ((u16*)outp)[(long)gi * 512 + gj] = f2bf(tanhf(c + bvec[gj]));
        }
      }
    }
  }
}

// ---------------- fused GAT attention: out = softmax_adj(lrelu(ald+als)) @ G ----
// single pass (logits bounded, no max subtraction). P tile 64x64 in LDS (stride 72).
__global__ __launch_bounds__(256)
void gat_attn(const unsigned char* __restrict__ adj,
              const float* __restrict__ ald, const float* __restrict__ als,
              const u16* __restrict__ gT, const float* __restrict__ bias,
              float* __restrict__ hf, u16* __restrict__ hall, int hall_off)
{
  __shared__ u16 P[64*72];
  __shared__ float sl[64];
  const int t = threadIdx.x, w = t >> 6, lane = t & 63;
  const int bz = blockIdx.y, i0 = blockIdx.x * 64;
  const int r = t >> 2, jq = (t & 3) * 16;
  const float ald_r = ald[(bz << 10) + i0 + r];
  const unsigned char* arow = adj + ((long)bz << 20) + ((long)(i0 + r) << 10);
  const float* als_b = als + (bz << 10);
  const u16* gTb = gT + ((long)bz << 17);
  const int rr = lane & 15, kb = (lane >> 4) * 8;
  float srow_s = 0.f;
  f32x4 acc[8] = {};

  for (int jt = 0; jt < 1024; jt += 64) {
    __syncthreads();   // previous MFMA done -> P reusable
    uint4 ab = *(const uint4*)(arow + jt + jq);
    float4 s0 = *(const float4*)(als_b + jt + jq);
    float4 s1 = *(const float4*)(als_b + jt + jq + 4);
    float4 s2 = *(const float4*)(als_b + jt + jq + 8);
    float4 s3 = *(const float4*)(als_b + jt + jq + 12);
    const u32 wds[4] = {ab.x, ab.y, ab.z, ab.w};
    const float sv[16] = {s0.x,s0.y,s0.z,s0.w, s1.x,s1.y,s1.z,s1.w,
                          s2.x,s2.y,s2.z,s2.w, s3.x,s3.y,s3.z,s3.w};
#pragma unroll
    for (int c = 0; c < 16; c++) {
      const u32 msk = (wds[c >> 2] >> ((c & 3) * 8)) & 255u;
      float x = ald_r + sv[c];
      x = x > 0.f ? x : 0.2f * x;
      const float p = msk ? __expf(x) : 0.f;
      srow_s += p;
      P[r*72 + jq + c] = f2bf(p);
    }
    __syncthreads();   // P ready
#pragma unroll
    for (int kk = 0; kk < 2; kk++) {
      const short8 a = *(const short8*)&P[(w*16 + rr)*72 + kk*32 + kb];
#pragma unroll
      for (int nf = 0; nf < 8; nf++) {
        const short8 b = *(const short8*)&gTb[(long)(nf*16 + rr) * 1024 + jt + kk*32 + kb];
        acc[nf] = __builtin_amdgcn_mfma_f32_16x16x32_bf16(a, b, acc[nf], 0, 0, 0);
      }
    }
  }
  srow_s += __shfl_xor(srow_s, 1, 64);
  srow_s += __shfl_xor(srow_s, 2, 64);
  if ((t & 3) == 0) sl[r] = srow_s;
  __syncthreads();
  const int row0 = w*16 + ((lane >> 4) << 2);
#pragma unroll
  for (int rg = 0; rg < 4; rg++) {
    const float s = sl[row0 + rg];
    const float inv = s > 0.f ? 1.f / s : 0.f;
    const long gi = ((long)bz << 10) + i0 + row0 + rg;
#pragma unroll
    for (int nf = 0; nf < 8; nf++) {
      const int c = nf*16 + (lane & 15);
      float v = acc[nf][rg] * inv + bias[c];
      v = v > 0.f ? v : 0.f;
      hf[gi*128 + c] = v;
      hall[gi*1024 + hall_off + c] = f2bf(v);
    }
  }
}

// ---------------- small kernels ----------------
__global__ __launch_bounds__(256)
void hn_kernel(const float* __restrict__ hidden, u16* __restrict__ hnb, u16* __restrict__ hall)
{
  const int row = blockIdx.x * 4 + (threadIdx.x >> 6);
  const int lane = threadIdx.x & 63;
  const float* h = hidden + (long)row * 768;
  float x[12]; float ss = 0.f;
#pragma unroll
  for (int k = 0; k < 12; k++) { x[k] = h[k*64 + lane]; ss += x[k]*x[k]; }
#pragma unroll
  for (int o = 32; o > 0; o >>= 1) ss += __shfl_xor(ss, o, 64);
  const float inv = 1.f / fmaxf(sqrtf(ss), 1e-8f);
#pragma unroll
  for (int k = 0; k < 12; k++) {
    hnb[(long)row*768  + k*64 + lane] = f2bf(x[k] * inv);
    hall[(long)row*1024 + k*64 + lane] = f2bf(x[k]);
  }
}

__global__ void transpose_bf(const float* __restrict__ in, u16* __restrict__ out, int K, int N)
{
  const int idx = blockIdx.x * 256 + threadIdx.x;
  if (idx >= K * N) return;
  const int k = idx / N, n = idx % N;
  out[(long)n * K + k] = f2bf(in[idx]);
}

__global__ void ae_kernel(const float* we0, const float* ao0, const float* we1, const float* ao1, float* out)
{
  __shared__ float s0[128], s1[128];
  const int t = threadIdx.x;
  s0[t] = we0[t] * ao0[t];
  s1[t] = we1[t] * ao1[t];
  __syncthreads();
  for (int o = 64; o > 0; o >>= 1) { if (t < o) { s0[t]+=s0[t+o]; s1[t]+=s1[t+o]; } __syncthreads(); }
  if (t == 0) { out[0] = s0[0]; out[1] = s1[0]; }
}

__global__ void al_kernel(const u16* __restrict__ gT,
                          const float* __restrict__ a_src, const float* __restrict__ a_dst,
                          const float* __restrict__ aeptr,
                          float* __restrict__ als, float* __restrict__ ald)
{
  const int b = blockIdx.y;
  const int l = blockIdx.x * 256 + threadIdx.x;
  const u16* g = gT + ((long)b << 17) + l;
  float ss = 0.f, sd = 0.f;
#pragma unroll 4
  for (int c = 0; c < 128; c++) {
    const float v = bf2f(g[(long)c << 10]);
    ss += v * a_src[c];
    sd += v * a_dst[c];
  }
  als[(b << 10) + l] = ss;
  ald[(b << 10) + l] = sd + aeptr[0];
}

__global__ __launch_bounds__(256)
void gemv_scores(const u16* __restrict__ tb, const float* __restrict__ S2W,
                 const float* __restrict__ S2b, float* __restrict__ scores)
{
  const int row = blockIdx.x * 4 + (threadIdx.x >> 6);
  const int lane = threadIdx.x & 63;
  const short8 v = *(const short8*)&tb[(long)row * 512 + lane * 8];
  float s = 0.f;
#pragma unroll
  for (int i = 0; i < 8; i++) s += bf2f((u16)v[i]) * S2W[lane*8 + i];
#pragma unroll
  for (int o = 32; o > 0; o >>= 1) s += __shfl_xor(s, o, 64);
  if (lane == 0) scores[row] = s + S2b[0];
}

__global__ void softmax_w(const float* __restrict__ scores, const int* __restrict__ valid,
                          float* __restrict__ wts)
{
  __shared__ float wsum[4];
  const int b = blockIdx.x, t = threadIdx.x;
  float e[4]; float part = 0.f;
#pragma unroll
  for (int q = 0; q < 4; q++) {
    const int l = q*256 + t;
    const float ex = valid[(b<<10) + l] ? __expf(scores[(b<<10) + l]) : 0.f;
    e[q] = ex; part += ex;
  }
#pragma unroll
  for (int o = 32; o > 0; o >>= 1) part += __shfl_xor(part, o, 64);
  if ((t & 63) == 0) wsum[t >> 6] = part;
  __syncthreads();
  const float total = wsum[0] + wsum[1] + wsum[2] + wsum[3];
  const float inv = 1.f / fmaxf(total, 1e-16f);
#pragma unroll
  for (int q = 0; q < 4; q++) wts[(b<<10) + q*256 + t] = e[q] * inv;
}

__global__ void zero_out_k(float* out){ out[blockIdx.x*256 + threadIdx.x] = 0.f; }

__global__ __launch_bounds__(256)
void pooled_kernel(const float* __restrict__ hidden, const float* __restrict__ h1f,
                   const float* __restrict__ h2f, const float* __restrict__ wts,
                   float* __restrict__ out)
{
  const int b = blockIdx.y, l0 = blockIdx.x * 64, t = threadIdx.x;
  float a0=0.f, a1=0.f, a2=0.f, a3=0.f;
  for (int l = 0; l < 64; l++) {
    const int gl = (b << 10) + l0 + l;
    const float wv = wts[gl];
    const float* hr = hidden + (long)gl * 768;
    a0 += wv * hr[t];
    a1 += wv * hr[256 + t];
    a2 += wv * hr[512 + t];
    const float v3 = (t < 128) ? h1f[(long)gl*128 + t] : h2f[(long)gl*128 + (t - 128)];
    a3 += wv * v3;
  }
  atomicAdd(&out[(b<<10) + t],        a0);
  atomicAdd(&out[(b<<10) + 256 + t],  a1);
  atomicAdd(&out[(b<<10) + 512 + t],  a2);
  atomicAdd(&out[(b<<10) + 768 + t],  a3);
}

// ---------------- launch ----------------
extern "C" void kernel_launch(void* const* d_in, const int* in_sizes, int n_in,
                              void* d_out, int out_size, void* d_ws, size_t ws_size,
                              hipStream_t stream)
{
  const float* hidden = (const float*)d_in[0];
  const int*   mask   = (const int*)d_in[1];
  const float* W0     = (const float*)d_in[2];
  const float* asrc0  = (const float*)d_in[3];
  const float* adst0  = (const float*)d_in[4];
  const float* wed0   = (const float*)d_in[5];
  const float* aed0   = (const float*)d_in[6];
  const float* bias0  = (const float*)d_in[7];
  const float* W1     = (const float*)d_in[8];
  const float* asrc1  = (const float*)d_in[9];
  const float* adst1  = (const float*)d_in[10];
  const float* wed1   = (const float*)d_in[11];
  const float* aed1   = (const float*)d_in[12];
  const float* bias1  = (const float*)d_in[13];
  const float* S1W    = (const float*)d_in[14];
  const float* S1b    = (const float*)d_in[15];
  const float* S2W    = (const float*)d_in[16];
  const float* S2b    = (const float*)d_in[17];
  float* out = (float*)d_out;

  char* ws = (char*)d_ws;
  u16* hall = (u16*)(ws + 0);                     // 16384x1024 bf16  (33554432 B)
  u16* hnb  = (u16*)(ws + 33554432);              // 16384x768 bf16   (25165824 B), reused as t
  u16* tb   = hnb;                                //  tanh buf 16384x512 bf16 (16 MB) fits
  unsigned char* adj = (unsigned char*)(ws + 58720256); // 16x1024x1024   (16777216 B)
  u16* gt   = (u16*)(ws + 75497472);              // 16x128x1024 bf16  (4194304 B)
  u16* w0t  = (u16*)(ws + 79691776);              // 128x768
  u16* w1t  = (u16*)(ws + 79888384);              // 128x128
  u16* s1t  = (u16*)(ws + 79921152);              // 512x1024
  float* ald = (float*)(ws + 80969728);           // 16x1024
  float* als = (float*)(ws + 81035264);           // 16x1024
  float* h1f = (float*)(ws + 81100800);           // 16x1024x128 f32
  float* h2f = (float*)(ws + 89489408);           // 16x1024x128 f32
  float* scores = (float*)(ws + 97878016);        // 16x1024
  float* wts    = (float*)(ws + 97943552);        // 16x1024
  float* aeb    = (float*)(ws + 98009088);        // 2 floats

  zero_out_k<<<64, 256, 0, stream>>>(out);
  ae_kernel<<<1, 128, 0, stream>>>(wed0, aed0, wed1, aed1, aeb);
  transpose_bf<<<384,  256, 0, stream>>>(W0,  w0t, 768, 128);
  transpose_bf<<<64,   256, 0, stream>>>(W1,  w1t, 128, 128);
  transpose_bf<<<2048, 256, 0, stream>>>(S1W, s1t, 1024, 512);
  hn_kernel<<<4096, 256, 0, stream>>>(hidden, hnb, hall);

  // adjacency: sim > TAU, batched NT GEMM on normalized rows
  gemm_nt<0><<<dim3(8,8,16), 256, 0, stream>>>(hnb, hnb, 768, 768, 768,
        (long)1024*768, (long)1024*768, adj, mask, nullptr);

  // layer 0
  gemm_nt<1><<<dim3(1,128,1), 256, 0, stream>>>(hall, w0t, 1024, 768, 768, 0, 0, gt, nullptr, nullptr);
  al_kernel<<<dim3(4,16), 256, 0, stream>>>(gt, asrc0, adst0, aeb, als, ald);
  gat_attn<<<dim3(16,16), 256, 0, stream>>>(adj, ald, als, gt, bias0, h1f, hall, 768);

  // layer 1
  gemm_nt<1><<<dim3(1,128,1), 256, 0, stream>>>(hall + 768, w1t, 1024, 128, 128, 0, 0, gt, nullptr, nullptr);
  al_kernel<<<dim3(4,16), 256, 0, stream>>>(gt, asrc1, adst1, aeb + 1, als, ald);
  gat_attn<<<dim3(16,16), 256, 0, stream>>>(adj, ald, als, gt, bias1, h2f, hall, 896);

  // scorer
  gemm_nt<2><<<dim3(4,128,1), 256, 0, stream>>>(hall, s1t, 1024, 1024, 1024, 0, 0, tb, nullptr, S1b);
  gemv_scores<<<4096, 256, 0, stream>>>(tb, S2W, S2b, scores);
  softmax_w<<<16, 256, 0, stream>>>(scores, mask, wts);
  pooled_kernel<<<dim3(16,16), 256, 0, stream>>>(hidden, h1f, h2f, wts, out);
}

// Round 2
// 324.433 us; speedup vs baseline: 1.0747x; 1.0747x over previous
//
#include <hip/hip_runtime.h>

typedef __attribute__((ext_vector_type(8))) short short8;
typedef __attribute__((ext_vector_type(4))) float f32x4;
typedef unsigned short u16;
typedef unsigned int u32;
typedef unsigned long long u64;

#define TAU_F 0.3f

__device__ __forceinline__ u16 f2bf(float f){
  u32 u = __float_as_uint(f);
  u32 r = u + 0x7FFFu + ((u >> 16) & 1u);
  return (u16)(r >> 16);
}
__device__ __forceinline__ float bf2f(u16 v){
  return __uint_as_float(((u32)v) << 16);
}

typedef __attribute__((address_space(1))) const u32 glb_u32;
typedef __attribute__((address_space(3))) u32 lds_u32;
__device__ __forceinline__ void async_lds16(const void* g, void* l){
  __builtin_amdgcn_global_load_lds((glb_u32*)g, (lds_u32*)l, 16, 0, 0);
}

// ---------------- generic bf16 NT GEMM, 128x128 tile, BK=32 (m97 structure) ----
// MODE 0: adj-byte epilogue (sim > TAU && valid_i && valid_j)
// MODE 1: gT store  (out[(b*128+c)*1024 + l] = bf16(acc)), b=row>>10, l=row&1023
// MODE 2: tanh(acc + bvec[col]) -> bf16, ldc=512
template<int MODE>
__global__ __launch_bounds__(256)
void gemm_nt(const u16* __restrict__ A, const u16* __restrict__ B,
             int lda, int ldb, int K, long sA, long sB,
             void* __restrict__ outp,
             const int* __restrict__ valid,
             const float* __restrict__ bvec)
{
  __shared__ u16 lA[128*32];
  __shared__ u16 lB[128*32];
  const int t = threadIdx.x;
  const int w = t >> 6, lane = t & 63;
  const int bz = blockIdx.z;
  const int i0 = blockIdx.y * 128, n0 = blockIdx.x * 128;
  const u16* Ab = A + (long)bz * sA;
  const u16* Bb = B + (long)bz * sB;
  const int wr = w >> 1, wc = w & 1;
  const int srow = t >> 2;         // 0..63 staging row
  const int scol = (t & 3) * 8;    // staging col (elems)
  const int rA = lane & 15, kb = (lane >> 4) * 8;
  f32x4 acc[4][4] = {};

  for (int kt = 0; kt < K; kt += 32) {
    __syncthreads();
    async_lds16(Ab + (long)(i0 +      srow) * lda + kt + scol, &lA[       w*512]);
    async_lds16(Ab + (long)(i0 + 64 + srow) * lda + kt + scol, &lA[2048 + w*512]);
    async_lds16(Bb + (long)(n0 +      srow) * ldb + kt + scol, &lB[       w*512]);
    async_lds16(Bb + (long)(n0 + 64 + srow) * ldb + kt + scol, &lB[2048 + w*512]);
    __syncthreads();
    short8 af[4], bfr[4];
#pragma unroll
    for (int m = 0; m < 4; m++)
      af[m] = *(const short8*)&lA[(wr*64 + m*16 + rA)*32 + kb];
#pragma unroll
    for (int n = 0; n < 4; n++)
      bfr[n] = *(const short8*)&lB[(wc*64 + n*16 + rA)*32 + kb];
#pragma unroll
    for (int m = 0; m < 4; m++)
#pragma unroll
      for (int n = 0; n < 4; n++)
        acc[m][n] = __builtin_amdgcn_mfma_f32_16x16x32_bf16(af[m], bfr[n], acc[m][n], 0, 0, 0);
  }

#pragma unroll
  for (int m = 0; m < 4; m++) {
    const int gi0 = i0 + wr*64 + m*16 + ((lane >> 4) << 2);
#pragma unroll
    for (int n = 0; n < 4; n++) {
      const int gj = n0 + wc*64 + n*16 + (lane & 15);
#pragma unroll
      for (int r = 0; r < 4; r++) {
        const int gi = gi0 + r;
        const float c = acc[m][n][r];
        if (MODE == 0) {
          unsigned char e = (c > TAU_F && valid[(bz<<10) + gi] && valid[(bz<<10) + gj]) ? 1 : 0;
          ((unsigned char*)outp)[((long)bz << 20) + ((long)gi << 10) + gj] = e;
        } else if (MODE == 1) {
          const int b = gi >> 10, l = gi & 1023;
          ((u16*)outp)[(((long)(b*128 + gj)) << 10) + l] = f2bf(c);
        } else {
          ((u16*)outp)[(long)gi * 512 + gj] = f2bf(tanhf(c + bvec[gj]));
        }
      }
    }
  }
}

// ---------------- fused GAT attention, barrier-free main loop ----------------
// Each wave: 32 dst rows (2 row-frags), one 256-wide j-chunk. P fragments are
// built in registers (A-frag layout: lane = row lane&15, k = (lane>>4)*8 + e).
// 4 waves (= 4 j-chunks) combine partial PV + row-sums via LDS atomics once.
__global__ __launch_bounds__(256)
void gat_attn(const unsigned char* __restrict__ adj,
              const float* __restrict__ ald, const float* __restrict__ als,
              const u16* __restrict__ gT, const float* __restrict__ bias,
              float* __restrict__ hf, u16* __restrict__ hall, int hall_off)
{
  __shared__ float red[32*128];
  __shared__ float ssum[32];
  const int t = threadIdx.x, w = t >> 6, lane = t & 63;
  const int bz = blockIdx.y, i0 = blockIdx.x * 32;
  const int rr = lane & 15, kg = lane >> 4;
  const int r0 = i0 + rr;
  const float ald0 = ald[(bz << 10) + r0];
  const float ald1 = ald[(bz << 10) + r0 + 16];
  const unsigned char* arow0 = adj + ((long)bz << 20) + ((long)r0 << 10);
  const unsigned char* arow1 = arow0 + (16 << 10);
  const float* als_b = als + (bz << 10);
  const u16* gTb = gT + ((long)bz << 17);
  float s0 = 0.f, s1 = 0.f;
  f32x4 acc0[8] = {}, acc1[8] = {};

  {
    const float4 z = {0.f, 0.f, 0.f, 0.f};
    *(float4*)&red[t*16]      = z;
    *(float4*)&red[t*16 + 4]  = z;
    *(float4*)&red[t*16 + 8]  = z;
    *(float4*)&red[t*16 + 12] = z;
    if (t < 32) ssum[t] = 0.f;
  }
  __syncthreads();

  const int jbase = w * 256 + kg * 8;
#pragma unroll 2
  for (int jt = 0; jt < 256; jt += 32) {
    const int jl = jbase + jt;
    const u64 a0 = *(const u64*)(arow0 + jl);
    const u64 a1 = *(const u64*)(arow1 + jl);
    const float4 f0 = *(const float4*)(als_b + jl);
    const float4 f1 = *(const float4*)(als_b + jl + 4);
    const float sv[8] = {f0.x, f0.y, f0.z, f0.w, f1.x, f1.y, f1.z, f1.w};
    short8 pa0, pa1;
#pragma unroll
    for (int e = 0; e < 8; e++) {
      float x0 = ald0 + sv[e];
      x0 = x0 > 0.f ? x0 : 0.2f * x0;
      const float p0 = ((a0 >> (8*e)) & 255ull) ? __expf(x0) : 0.f;
      s0 += p0; pa0[e] = (short)f2bf(p0);
      float x1 = ald1 + sv[e];
      x1 = x1 > 0.f ? x1 : 0.2f * x1;
      const float p1 = ((a1 >> (8*e)) & 255ull) ? __expf(x1) : 0.f;
      s1 += p1; pa1[e] = (short)f2bf(p1);
    }
#pragma unroll
    for (int nf = 0; nf < 8; nf++) {
      const short8 b = *(const short8*)&gTb[(long)(nf*16 + rr) * 1024 + jl];
      acc0[nf] = __builtin_amdgcn_mfma_f32_16x16x32_bf16(pa0, b, acc0[nf], 0, 0, 0);
      acc1[nf] = __builtin_amdgcn_mfma_f32_16x16x32_bf16(pa1, b, acc1[nf], 0, 0, 0);
    }
  }

  // reduce row sums across the 4 k-groups of the wave
  s0 += __shfl_xor(s0, 16, 64); s0 += __shfl_xor(s0, 32, 64);
  s1 += __shfl_xor(s1, 16, 64); s1 += __shfl_xor(s1, 32, 64);
  if (lane < 16) {
    atomicAdd(&ssum[lane],      s0);
    atomicAdd(&ssum[lane + 16], s1);
  }
#pragma unroll
  for (int nf = 0; nf < 8; nf++)
#pragma unroll
    for (int rg = 0; rg < 4; rg++) {
      atomicAdd(&red[(kg*4 + rg)*128      + nf*16 + rr], acc0[nf][rg]);
      atomicAdd(&red[(16 + kg*4 + rg)*128 + nf*16 + rr], acc1[nf][rg]);
    }
  __syncthreads();

  // epilogue: normalize, bias, relu; write fp32 h and bf16 slice of hall
  const int r = t >> 3, cg = (t & 7) * 16;
  const float sm = ssum[r];
  const float inv = sm > 0.f ? 1.f / sm : 0.f;
  const long gi = ((long)bz << 10) + i0 + r;
  float* hrow = hf + gi * 128;
  u16* orow = hall + gi * 1024 + hall_off;
#pragma unroll
  for (int q = 0; q < 16; q++) {
    float v = red[r*128 + cg + q] * inv + bias[cg + q];
    v = v > 0.f ? v : 0.f;
    hrow[cg + q] = v;
    orow[cg + q] = f2bf(v);
  }
}

// ---------------- small kernels ----------------
__global__ __launch_bounds__(256)
void hn_kernel(const float* __restrict__ hidden, u16* __restrict__ hnb, u16* __restrict__ hall)
{
  const int row = blockIdx.x * 4 + (threadIdx.x >> 6);
  const int lane = threadIdx.x & 63;
  const float* h = hidden + (long)row * 768;
  float x[12]; float ss = 0.f;
#pragma unroll
  for (int k = 0; k < 12; k++) { x[k] = h[k*64 + lane]; ss += x[k]*x[k]; }
#pragma unroll
  for (int o = 32; o > 0; o >>= 1) ss += __shfl_xor(ss, o, 64);
  const float inv = 1.f / fmaxf(sqrtf(ss), 1e-8f);
#pragma unroll
  for (int k = 0; k < 12; k++) {
    hnb[(long)row*768  + k*64 + lane] = f2bf(x[k] * inv);
    hall[(long)row*1024 + k*64 + lane] = f2bf(x[k]);
  }
}

__global__ void transpose_bf(const float* __restrict__ in, u16* __restrict__ out, int K, int N)
{
  const int idx = blockIdx.x * 256 + threadIdx.x;
  if (idx >= K * N) return;
  const int k = idx / N, n = idx % N;
  out[(long)n * K + k] = f2bf(in[idx]);
}

__global__ void ae_kernel(const float* we0, const float* ao0, const float* we1, const float* ao1, float* out)
{
  __shared__ float s0[128], s1[128];
  const int t = threadIdx.x;
  s0[t] = we0[t] * ao0[t];
  s1[t] = we1[t] * ao1[t];
  __syncthreads();
  for (int o = 64; o > 0; o >>= 1) { if (t < o) { s0[t]+=s0[t+o]; s1[t]+=s1[t+o]; } __syncthreads(); }
  if (t == 0) { out[0] = s0[0]; out[1] = s1[0]; }
}

__global__ void al_kernel(const u16* __restrict__ gT,
                          const float* __restrict__ a_src, const float* __restrict__ a_dst,
                          const float* __restrict__ aeptr,
                          float* __restrict__ als, float* __restrict__ ald)
{
  const int b = blockIdx.y;
  const int l = blockIdx.x * 256 + threadIdx.x;
  const u16* g = gT + ((long)b << 17) + l;
  float ss = 0.f, sd = 0.f;
#pragma unroll 4
  for (int c = 0; c < 128; c++) {
    const float v = bf2f(g[(long)c << 10]);
    ss += v * a_src[c];
    sd += v * a_dst[c];
  }
  als[(b << 10) + l] = ss;
  ald[(b << 10) + l] = sd + aeptr[0];
}

__global__ __launch_bounds__(256)
void gemv_scores(const u16* __restrict__ tb, const float* __restrict__ S2W,
                 const float* __restrict__ S2b, float* __restrict__ scores)
{
  const int row = blockIdx.x * 4 + (threadIdx.x >> 6);
  const int lane = threadIdx.x & 63;
  const short8 v = *(const short8*)&tb[(long)row * 512 + lane * 8];
  float s = 0.f;
#pragma unroll
  for (int i = 0; i < 8; i++) s += bf2f((u16)v[i]) * S2W[lane*8 + i];
#pragma unroll
  for (int o = 32; o > 0; o >>= 1) s += __shfl_xor(s, o, 64);
  if (lane == 0) scores[row] = s + S2b[0];
}

__global__ void softmax_w(const float* __restrict__ scores, const int* __restrict__ valid,
                          float* __restrict__ wts)
{
  __shared__ float wsum[4];
  const int b = blockIdx.x, t = threadIdx.x;
  float e[4]; float part = 0.f;
#pragma unroll
  for (int q = 0; q < 4; q++) {
    const int l = q*256 + t;
    const float ex = valid[(b<<10) + l] ? __expf(scores[(b<<10) + l]) : 0.f;
    e[q] = ex; part += ex;
  }
#pragma unroll
  for (int o = 32; o > 0; o >>= 1) part += __shfl_xor(part, o, 64);
  if ((t & 63) == 0) wsum[t >> 6] = part;
  __syncthreads();
  const float total = wsum[0] + wsum[1] + wsum[2] + wsum[3];
  const float inv = 1.f / fmaxf(total, 1e-16f);
#pragma unroll
  for (int q = 0; q < 4; q++) wts[(b<<10) + q*256 + t] = e[q] * inv;
}

__global__ void zero_out_k(float* out){ out[blockIdx.x*256 + threadIdx.x] = 0.f; }

__global__ __launch_bounds__(256)
void pooled_kernel(const float* __restrict__ hidden, const float* __restrict__ h1f,
                   const float* __restrict__ h2f, const float* __restrict__ wts,
                   float* __restrict__ out)
{
  const int b = blockIdx.y, l0 = blockIdx.x * 64, t = threadIdx.x;
  float a0=0.f, a1=0.f, a2=0.f, a3=0.f;
  for (int l = 0; l < 64; l++) {
    const int gl = (b << 10) + l0 + l;
    const float wv = wts[gl];
    const float* hr = hidden + (long)gl * 768;
    a0 += wv * hr[t];
    a1 += wv * hr[256 + t];
    a2 += wv * hr[512 + t];
    const float v3 = (t < 128) ? h1f[(long)gl*128 + t] : h2f[(long)gl*128 + (t - 128)];
    a3 += wv * v3;
  }
  atomicAdd(&out[(b<<10) + t],        a0);
  atomicAdd(&out[(b<<10) + 256 + t],  a1);
  atomicAdd(&out[(b<<10) + 512 + t],  a2);
  atomicAdd(&out[(b<<10) + 768 + t],  a3);
}

// ---------------- launch ----------------
extern "C" void kernel_launch(void* const* d_in, const int* in_sizes, int n_in,
                              void* d_out, int out_size, void* d_ws, size_t ws_size,
                              hipStream_t stream)
{
  const float* hidden = (const float*)d_in[0];
  const int*   mask   = (const int*)d_in[1];
  const float* W0     = (const float*)d_in[2];
  const float* asrc0  = (const float*)d_in[3];
  const float* adst0  = (const float*)d_in[4];
  const float* wed0   = (const float*)d_in[5];
  const float* aed0   = (const float*)d_in[6];
  const float* bias0  = (const float*)d_in[7];
  const float* W1     = (const float*)d_in[8];
  const float* asrc1  = (const float*)d_in[9];
  const float* adst1  = (const float*)d_in[10];
  const float* wed1   = (const float*)d_in[11];
  const float* aed1   = (const float*)d_in[12];
  const float* bias1  = (const float*)d_in[13];
  const float* S1W    = (const float*)d_in[14];
  const float* S1b    = (const float*)d_in[15];
  const float* S2W    = (const float*)d_in[16];
  const float* S2b    = (const float*)d_in[17];
  float* out = (float*)d_out;

  char* ws = (char*)d_ws;
  u16* hall = (u16*)(ws + 0);                     // 16384x1024 bf16  (33554432 B)
  u16* hnb  = (u16*)(ws + 33554432);              // 16384x768 bf16   (25165824 B), reused as tb
  u16* tb   = hnb;                                // tanh buf 16384x512 bf16 (16 MB) fits
  unsigned char* adj = (unsigned char*)(ws + 58720256); // 16x1024x1024   (16777216 B)
  u16* gt   = (u16*)(ws + 75497472);              // 16x128x1024 bf16  (4194304 B)
  u16* w0t  = (u16*)(ws + 79691776);              // 128x768
  u16* w1t  = (u16*)(ws + 79888384);              // 128x128
  u16* s1t  = (u16*)(ws + 79921152);              // 512x1024
  float* ald = (float*)(ws + 80969728);           // 16x1024
  float* als = (float*)(ws + 81035264);           // 16x1024
  float* h1f = (float*)(ws + 81100800);           // 16x1024x128 f32
  float* h2f = (float*)(ws + 89489408);           // 16x1024x128 f32
  float* scores = (float*)(ws + 97878016);        // 16x1024
  float* wts    = (float*)(ws + 97943552);        // 16x1024
  float* aeb    = (float*)(ws + 98009088);        // 2 floats

  zero_out_k<<<64, 256, 0, stream>>>(out);
  ae_kernel<<<1, 128, 0, stream>>>(wed0, aed0, wed1, aed1, aeb);
  transpose_bf<<<384,  256, 0, stream>>>(W0,  w0t, 768, 128);
  transpose_bf<<<64,   256, 0, stream>>>(W1,  w1t, 128, 128);
  transpose_bf<<<2048, 256, 0, stream>>>(S1W, s1t, 1024, 512);
  hn_kernel<<<4096, 256, 0, stream>>>(hidden, hnb, hall);

  // adjacency: sim > TAU, batched NT GEMM on normalized rows
  gemm_nt<0><<<dim3(8,8,16), 256, 0, stream>>>(hnb, hnb, 768, 768, 768,
        (long)1024*768, (long)1024*768, adj, mask, nullptr);

  // layer 0
  gemm_nt<1><<<dim3(1,128,1), 256, 0, stream>>>(hall, w0t, 1024, 768, 768, 0, 0, gt, nullptr, nullptr);
  al_kernel<<<dim3(4,16), 256, 0, stream>>>(gt, asrc0, adst0, aeb, als, ald);
  gat_attn<<<dim3(32,16), 256, 0, stream>>>(adj, ald, als, gt, bias0, h1f, hall, 768);

  // layer 1
  gemm_nt<1><<<dim3(1,128,1), 256, 0, stream>>>(hall + 768, w1t, 1024, 128, 128, 0, 0, gt, nullptr, nullptr);
  al_kernel<<<dim3(4,16), 256, 0, stream>>>(gt, asrc1, adst1, aeb + 1, als, ald);
  gat_attn<<<dim3(32,16), 256, 0, stream>>>(adj, ald, als, gt, bias1, h2f, hall, 896);

  // scorer
  gemm_nt<2><<<dim3(4,128,1), 256, 0, stream>>>(hall, s1t, 1024, 1024, 1024, 0, 0, tb, nullptr, S1b);
  gemv_scores<<<4096, 256, 0, stream>>>(tb, S2W, S2b, scores);
  softmax_w<<<16, 256, 0, stream>>>(scores, mask, wts);
  pooled_kernel<<<dim3(16,16), 256, 0, stream>>>(hidden, h1f, h2f, wts, out);
}

// Round 3
// 216.123 us; speedup vs baseline: 1.6133x; 1.5011x over previous
//
#include <hip/hip_runtime.h>

typedef __attribute__((ext_vector_type(8))) short short8;
typedef __attribute__((ext_vector_type(4))) float f32x4;
typedef unsigned short u16;
typedef unsigned int u32;
typedef unsigned long long u64;

#define TAU_F 0.3f

__device__ __forceinline__ u16 f2bf(float f){
  u32 u = __float_as_uint(f);
  u32 r = u + 0x7FFFu + ((u >> 16) & 1u);
  return (u16)(r >> 16);
}
__device__ __forceinline__ float bf2f(u16 v){
  return __uint_as_float(((u32)v) << 16);
}

typedef __attribute__((address_space(1))) const u32 glb_u32;
typedef __attribute__((address_space(3))) u32 lds_u32;
__device__ __forceinline__ void async_lds16(const void* g, void* l){
  __builtin_amdgcn_global_load_lds((glb_u32*)g, (lds_u32*)l, 16, 0, 0);
}

// ---------------- generic bf16 NT GEMM, 128x128 tile, BK=32 (m97 structure) ----
// MODE 0: adj-byte epilogue (sim > TAU && valid_i && valid_j)
// MODE 1: gT store  (out[(b*128+c)*1024 + l] = bf16(acc)), b=row>>10, l=row&1023
// MODE 2: tanh(acc + bvec[col]) -> bf16, ldc=512
template<int MODE>
__global__ __launch_bounds__(256)
void gemm_nt(const u16* __restrict__ A, const u16* __restrict__ B,
             int lda, int ldb, int K, long sA, long sB,
             void* __restrict__ outp,
             const int* __restrict__ valid,
             const float* __restrict__ bvec)
{
  __shared__ u16 lA[128*32];
  __shared__ u16 lB[128*32];
  const int t = threadIdx.x;
  const int w = t >> 6, lane = t & 63;
  const int bz = blockIdx.z;
  const int i0 = blockIdx.y * 128, n0 = blockIdx.x * 128;
  const u16* Ab = A + (long)bz * sA;
  const u16* Bb = B + (long)bz * sB;
  const int wr = w >> 1, wc = w & 1;
  const int srow = t >> 2;         // 0..63 staging row
  const int scol = (t & 3) * 8;    // staging col (elems)
  const int rA = lane & 15, kb = (lane >> 4) * 8;
  f32x4 acc[4][4] = {};

  for (int kt = 0; kt < K; kt += 32) {
    __syncthreads();
    async_lds16(Ab + (long)(i0 +      srow) * lda + kt + scol, &lA[       w*512]);
    async_lds16(Ab + (long)(i0 + 64 + srow) * lda + kt + scol, &lA[2048 + w*512]);
    async_lds16(Bb + (long)(n0 +      srow) * ldb + kt + scol, &lB[       w*512]);
    async_lds16(Bb + (long)(n0 + 64 + srow) * ldb + kt + scol, &lB[2048 + w*512]);
    __syncthreads();
    short8 af[4], bfr[4];
#pragma unroll
    for (int m = 0; m < 4; m++)
      af[m] = *(const short8*)&lA[(wr*64 + m*16 + rA)*32 + kb];
#pragma unroll
    for (int n = 0; n < 4; n++)
      bfr[n] = *(const short8*)&lB[(wc*64 + n*16 + rA)*32 + kb];
#pragma unroll
    for (int m = 0; m < 4; m++)
#pragma unroll
      for (int n = 0; n < 4; n++)
        acc[m][n] = __builtin_amdgcn_mfma_f32_16x16x32_bf16(af[m], bfr[n], acc[m][n], 0, 0, 0);
  }

#pragma unroll
  for (int m = 0; m < 4; m++) {
    const int gi0 = i0 + wr*64 + m*16 + ((lane >> 4) << 2);
#pragma unroll
    for (int n = 0; n < 4; n++) {
      const int gj = n0 + wc*64 + n*16 + (lane & 15);
#pragma unroll
      for (int r = 0; r < 4; r++) {
        const int gi = gi0 + r;
        const float c = acc[m][n][r];
        if (MODE == 0) {
          unsigned char e = (c > TAU_F && valid[(bz<<10) + gi] && valid[(bz<<10) + gj]) ? 1 : 0;
          ((unsigned char*)outp)[((long)bz << 20) + ((long)gi << 10) + gj] = e;
        } else if (MODE == 1) {
          const int b = gi >> 10, l = gi & 1023;
          ((u16*)outp)[(((long)(b*128 + gj)) << 10) + l] = f2bf(c);
        } else {
          ((u16*)outp)[(long)gi * 512 + gj] = f2bf(tanhf(c + bvec[gj]));
        }
      }
    }
  }
}

// ---------------- fused GAT attention, sparsity-skipping ----------------
// Wave = 16 dst rows x full 128 cols, j-chunk of 256 (8 steps of 32).
// Adjacency words prefetched; a 32-j step with no edges in the wave is
// skipped entirely (zero mask => zero P contribution => exact).
// 4 waves (4 j-chunks of one row-tile) combine via per-wave LDS slices.
__global__ __launch_bounds__(256)
void gat_attn(const unsigned char* __restrict__ adj,
              const float* __restrict__ ald, const float* __restrict__ als,
              const u16* __restrict__ gT, const float* __restrict__ bias,
              float* __restrict__ hf, u16* __restrict__ hall, int hall_off)
{
  __shared__ float red[4][16][132];
  __shared__ float ssumw[4][16];
  const int t = threadIdx.x, w = t >> 6, lane = t & 63;
  const int bz = blockIdx.y, i0 = blockIdx.x * 16;
  const int rr = lane & 15, kg = lane >> 4;
  const int r0 = i0 + rr;
  const float ald0 = ald[(bz << 10) + r0];
  const unsigned char* arow = adj + ((long)bz << 20) + ((long)r0 << 10);
  const float* als_b = als + (bz << 10);
  const u16* gTb = gT + ((long)bz << 17);
  float s0 = 0.f;
  f32x4 acc[8] = {};
  const int jbase = w * 256 + kg * 8;

  u64 aw[8];
#pragma unroll
  for (int it = 0; it < 8; it++)
    aw[it] = *(const u64*)(arow + jbase + it*32);

#pragma unroll
  for (int it = 0; it < 8; it++) {
    const u64 a0 = aw[it];
    if (__any(a0 != 0ull)) {
      const int jl = jbase + it*32;
      const float4 f0 = *(const float4*)(als_b + jl);
      const float4 f1 = *(const float4*)(als_b + jl + 4);
      const float sv[8] = {f0.x, f0.y, f0.z, f0.w, f1.x, f1.y, f1.z, f1.w};
      short8 pa;
#pragma unroll
      for (int e = 0; e < 8; e++) {
        float x = ald0 + sv[e];
        x = x > 0.f ? x : 0.2f * x;
        const float p = ((a0 >> (8*e)) & 255ull) ? __expf(x) : 0.f;
        s0 += p;
        pa[e] = (short)f2bf(p);
      }
#pragma unroll
      for (int nf = 0; nf < 8; nf++) {
        const short8 b = *(const short8*)&gTb[(long)(nf*16 + rr) * 1024 + jl];
        acc[nf] = __builtin_amdgcn_mfma_f32_16x16x32_bf16(pa, b, acc[nf], 0, 0, 0);
      }
    }
  }

  // row-sum: combine the 4 k-groups of the wave
  s0 += __shfl_xor(s0, 16, 64);
  s0 += __shfl_xor(s0, 32, 64);
  if (lane < 16) ssumw[w][lane] = s0;
  // partial PV into this wave's LDS slice (C-frag: row=kg*4+rg, col=nf*16+rr)
#pragma unroll
  for (int nf = 0; nf < 8; nf++)
#pragma unroll
    for (int rg = 0; rg < 4; rg++)
      red[w][kg*4 + rg][nf*16 + rr] = acc[nf][rg];
  __syncthreads();

  // epilogue: 256 threads cover 16 rows x 128 cols (8 cols each)
  const int r = t >> 4, c0 = (t & 15) * 8;
  const float sm = ssumw[0][r] + ssumw[1][r] + ssumw[2][r] + ssumw[3][r];
  const float inv = sm > 0.f ? 1.f / sm : 0.f;
  const long gi = ((long)bz << 10) + i0 + r;
  float* hrow = hf + gi * 128;
  u16* orow = hall + gi * 1024 + hall_off;
#pragma unroll
  for (int q = 0; q < 8; q++) {
    const int c = c0 + q;
    float v = (red[0][r][c] + red[1][r][c] + red[2][r][c] + red[3][r][c]) * inv + bias[c];
    v = v > 0.f ? v : 0.f;
    hrow[c] = v;
    orow[c] = f2bf(v);
  }
}

// ---------------- small kernels ----------------
__global__ __launch_bounds__(256)
void hn_kernel(const float* __restrict__ hidden, u16* __restrict__ hnb, u16* __restrict__ hall)
{
  const int row = blockIdx.x * 4 + (threadIdx.x >> 6);
  const int lane = threadIdx.x & 63;
  const float* h = hidden + (long)row * 768;
  float x[12]; float ss = 0.f;
#pragma unroll
  for (int k = 0; k < 12; k++) { x[k] = h[k*64 + lane]; ss += x[k]*x[k]; }
#pragma unroll
  for (int o = 32; o > 0; o >>= 1) ss += __shfl_xor(ss, o, 64);
  const float inv = 1.f / fmaxf(sqrtf(ss), 1e-8f);
#pragma unroll
  for (int k = 0; k < 12; k++) {
    hnb[(long)row*768  + k*64 + lane] = f2bf(x[k] * inv);
    hall[(long)row*1024 + k*64 + lane] = f2bf(x[k]);
  }
}

__global__ void transpose_bf(const float* __restrict__ in, u16* __restrict__ out, int K, int N)
{
  const int idx = blockIdx.x * 256 + threadIdx.x;
  if (idx >= K * N) return;
  const int k = idx / N, n = idx % N;
  out[(long)n * K + k] = f2bf(in[idx]);
}

__global__ void ae_kernel(const float* we0, const float* ao0, const float* we1, const float* ao1, float* out)
{
  __shared__ float s0[128], s1[128];
  const int t = threadIdx.x;
  s0[t] = we0[t] * ao0[t];
  s1[t] = we1[t] * ao1[t];
  __syncthreads();
  for (int o = 64; o > 0; o >>= 1) { if (t < o) { s0[t]+=s0[t+o]; s1[t]+=s1[t+o]; } __syncthreads(); }
  if (t == 0) { out[0] = s0[0]; out[1] = s1[0]; }
}

__global__ void al_kernel(const u16* __restrict__ gT,
                          const float* __restrict__ a_src, const float* __restrict__ a_dst,
                          const float* __restrict__ aeptr,
                          float* __restrict__ als, float* __restrict__ ald)
{
  const int b = blockIdx.y;
  const int l = blockIdx.x * 256 + threadIdx.x;
  const u16* g = gT + ((long)b << 17) + l;
  float ss = 0.f, sd = 0.f;
#pragma unroll 4
  for (int c = 0; c < 128; c++) {
    const float v = bf2f(g[(long)c << 10]);
    ss += v * a_src[c];
    sd += v * a_dst[c];
  }
  als[(b << 10) + l] = ss;
  ald[(b << 10) + l] = sd + aeptr[0];
}

__global__ __launch_bounds__(256)
void gemv_scores(const u16* __restrict__ tb, const float* __restrict__ S2W,
                 const float* __restrict__ S2b, float* __restrict__ scores)
{
  const int row = blockIdx.x * 4 + (threadIdx.x >> 6);
  const int lane = threadIdx.x & 63;
  const short8 v = *(const short8*)&tb[(long)row * 512 + lane * 8];
  float s = 0.f;
#pragma unroll
  for (int i = 0; i < 8; i++) s += bf2f((u16)v[i]) * S2W[lane*8 + i];
#pragma unroll
  for (int o = 32; o > 0; o >>= 1) s += __shfl_xor(s, o, 64);
  if (lane == 0) scores[row] = s + S2b[0];
}

__global__ void softmax_w(const float* __restrict__ scores, const int* __restrict__ valid,
                          float* __restrict__ wts)
{
  __shared__ float wsum[4];
  const int b = blockIdx.x, t = threadIdx.x;
  float e[4]; float part = 0.f;
#pragma unroll
  for (int q = 0; q < 4; q++) {
    const int l = q*256 + t;
    const float ex = valid[(b<<10) + l] ? __expf(scores[(b<<10) + l]) : 0.f;
    e[q] = ex; part += ex;
  }
#pragma unroll
  for (int o = 32; o > 0; o >>= 1) part += __shfl_xor(part, o, 64);
  if ((t & 63) == 0) wsum[t >> 6] = part;
  __syncthreads();
  const float total = wsum[0] + wsum[1] + wsum[2] + wsum[3];
  const float inv = 1.f / fmaxf(total, 1e-16f);
#pragma unroll
  for (int q = 0; q < 4; q++) wts[(b<<10) + q*256 + t] = e[q] * inv;
}

__global__ void zero_out_k(float* out){ out[blockIdx.x*256 + threadIdx.x] = 0.f; }

__global__ __launch_bounds__(256)
void pooled_kernel(const float* __restrict__ hidden, const float* __restrict__ h1f,
                   const float* __restrict__ h2f, const float* __restrict__ wts,
                   float* __restrict__ out)
{
  const int b = blockIdx.y, l0 = blockIdx.x * 64, t = threadIdx.x;
  float a0=0.f, a1=0.f, a2=0.f, a3=0.f;
  for (int l = 0; l < 64; l++) {
    const int gl = (b << 10) + l0 + l;
    const float wv = wts[gl];
    const float* hr = hidden + (long)gl * 768;
    a0 += wv * hr[t];
    a1 += wv * hr[256 + t];
    a2 += wv * hr[512 + t];
    const float v3 = (t < 128) ? h1f[(long)gl*128 + t] : h2f[(long)gl*128 + (t - 128)];
    a3 += wv * v3;
  }
  atomicAdd(&out[(b<<10) + t],        a0);
  atomicAdd(&out[(b<<10) + 256 + t],  a1);
  atomicAdd(&out[(b<<10) + 512 + t],  a2);
  atomicAdd(&out[(b<<10) + 768 + t],  a3);
}

// ---------------- launch ----------------
extern "C" void kernel_launch(void* const* d_in, const int* in_sizes, int n_in,
                              void* d_out, int out_size, void* d_ws, size_t ws_size,
                              hipStream_t stream)
{
  const float* hidden = (const float*)d_in[0];
  const int*   mask   = (const int*)d_in[1];
  const float* W0     = (const float*)d_in[2];
  const float* asrc0  = (const float*)d_in[3];
  const float* adst0  = (const float*)d_in[4];
  const float* wed0   = (const float*)d_in[5];
  const float* aed0   = (const float*)d_in[6];
  const float* bias0  = (const float*)d_in[7];
  const float* W1     = (const float*)d_in[8];
  const float* asrc1  = (const float*)d_in[9];
  const float* adst1  = (const float*)d_in[10];
  const float* wed1   = (const float*)d_in[11];
  const float* aed1   = (const float*)d_in[12];
  const float* bias1  = (const float*)d_in[13];
  const float* S1W    = (const float*)d_in[14];
  const float* S1b    = (const float*)d_in[15];
  const float* S2W    = (const float*)d_in[16];
  const float* S2b    = (const float*)d_in[17];
  float* out = (float*)d_out;

  char* ws = (char*)d_ws;
  u16* hall = (u16*)(ws + 0);                     // 16384x1024 bf16  (33554432 B)
  u16* hnb  = (u16*)(ws + 33554432);              // 16384x768 bf16   (25165824 B), reused as tb
  u16* tb   = hnb;                                // tanh buf 16384x512 bf16 (16 MB) fits
  unsigned char* adj = (unsigned char*)(ws + 58720256); // 16x1024x1024   (16777216 B)
  u16* gt   = (u16*)(ws + 75497472);              // 16x128x1024 bf16  (4194304 B)
  u16* w0t  = (u16*)(ws + 79691776);              // 128x768
  u16* w1t  = (u16*)(ws + 79888384);              // 128x128
  u16* s1t  = (u16*)(ws + 79921152);              // 512x1024
  float* ald = (float*)(ws + 80969728);           // 16x1024
  float* als = (float*)(ws + 81035264);           // 16x1024
  float* h1f = (float*)(ws + 81100800);           // 16x1024x128 f32
  float* h2f = (float*)(ws + 89489408);           // 16x1024x128 f32
  float* scores = (float*)(ws + 97878016);        // 16x1024
  float* wts    = (float*)(ws + 97943552);        // 16x1024
  float* aeb    = (float*)(ws + 98009088);        // 2 floats

  zero_out_k<<<64, 256, 0, stream>>>(out);
  ae_kernel<<<1, 128, 0, stream>>>(wed0, aed0, wed1, aed1, aeb);
  transpose_bf<<<384,  256, 0, stream>>>(W0,  w0t, 768, 128);
  transpose_bf<<<64,   256, 0, stream>>>(W1,  w1t, 128, 128);
  transpose_bf<<<2048, 256, 0, stream>>>(S1W, s1t, 1024, 512);
  hn_kernel<<<4096, 256, 0, stream>>>(hidden, hnb, hall);

  // adjacency: sim > TAU, batched NT GEMM on normalized rows
  gemm_nt<0><<<dim3(8,8,16), 256, 0, stream>>>(hnb, hnb, 768, 768, 768,
        (long)1024*768, (long)1024*768, adj, mask, nullptr);

  // layer 0
  gemm_nt<1><<<dim3(1,128,1), 256, 0, stream>>>(hall, w0t, 1024, 768, 768, 0, 0, gt, nullptr, nullptr);
  al_kernel<<<dim3(4,16), 256, 0, stream>>>(gt, asrc0, adst0, aeb, als, ald);
  gat_attn<<<dim3(64,16), 256, 0, stream>>>(adj, ald, als, gt, bias0, h1f, hall, 768);

  // layer 1
  gemm_nt<1><<<dim3(1,128,1), 256, 0, stream>>>(hall + 768, w1t, 1024, 128, 128, 0, 0, gt, nullptr, nullptr);
  al_kernel<<<dim3(4,16), 256, 0, stream>>>(gt, asrc1, adst1, aeb + 1, als, ald);
  gat_attn<<<dim3(64,16), 256, 0, stream>>>(adj, ald, als, gt, bias1, h2f, hall, 896);

  // scorer
  gemm_nt<2><<<dim3(4,128,1), 256, 0, stream>>>(hall, s1t, 1024, 1024, 1024, 0, 0, tb, nullptr, S1b);
  gemv_scores<<<4096, 256, 0, stream>>>(tb, S2W, S2b, scores);
  softmax_w<<<16, 256, 0, stream>>>(scores, mask, wts);
  pooled_kernel<<<dim3(16,16), 256, 0, stream>>>(hidden, h1f, h2f, wts, out);
}

// Round 4
// 202.760 us; speedup vs baseline: 1.7197x; 1.0659x over previous
//
#include <hip/hip_runtime.h>

typedef __attribute__((ext_vector_type(8))) short short8;
typedef __attribute__((ext_vector_type(4))) float f32x4;
typedef unsigned short u16;
typedef unsigned int u32;
typedef unsigned long long u64;

#define TAU_F 0.3f

__device__ __forceinline__ u16 f2bf(float f){
  u32 u = __float_as_uint(f);
  u32 r = u + 0x7FFFu + ((u >> 16) & 1u);
  return (u16)(r >> 16);
}
__device__ __forceinline__ float bf2f(u16 v){
  return __uint_as_float(((u32)v) << 16);
}

typedef __attribute__((address_space(1))) const u32 glb_u32;
typedef __attribute__((address_space(3))) u32 lds_u32;
__device__ __forceinline__ void async_lds16(const void* g, void* l){
  __builtin_amdgcn_global_load_lds((glb_u32*)g, (lds_u32*)l, 16, 0, 0);
}

// ---------------- compaction: per-batch valid-node count + index list --------
__global__ __launch_bounds__(1024)
void compact_kernel(const int* __restrict__ mask, int* __restrict__ cnt, int* __restrict__ idx)
{
  __shared__ int wtot[16];
  __shared__ int woff[16];
  const int b = blockIdx.x, t = threadIdx.x;
  const int w = t >> 6, lane = t & 63;
  const int m = mask[(b << 10) + t];
  const u64 bal = __ballot(m != 0);
  const int pos = __popcll(bal & ((1ull << lane) - 1ull));
  if (lane == 0) wtot[w] = __popcll(bal);
  __syncthreads();
  if (t == 0) {
    int acc = 0;
    for (int i = 0; i < 16; i++) { woff[i] = acc; acc += wtot[i]; }
    cnt[b] = acc;
  }
  __syncthreads();
  if (m) idx[(b << 10) + woff[w] + pos] = t;
}

// ---------------- generic bf16 NT GEMM, BMx128 tile, BK=32 -------------------
// MODE 0: adj-byte epilogue (sim > TAU, guarded to [0,cnt)^2; pad pre-zeroed)
// MODE 1: gT store  (out[(b*128+c)*1024 + l] = bf16(acc)), b=row>>10, l=row&1023
// MODE 2: tanh(acc + bvec[col]) -> bf16, ldc=512
// `cnt` = per-batch compacted row count (early-exit + guards).
template<int MODE, int BM>
__global__ __launch_bounds__(256)
void gemm_nt(const u16* __restrict__ A, const u16* __restrict__ B,
             int lda, int ldb, int K, long sA, long sB,
             void* __restrict__ outp,
             const int* __restrict__ cnt,
             const float* __restrict__ bvec)
{
  __shared__ u16 lA[BM*32];
  __shared__ u16 lB[128*32];
  const int t = threadIdx.x;
  const int w = t >> 6, lane = t & 63;
  const int bz = blockIdx.z;
  const int i0 = blockIdx.y * BM, n0 = blockIdx.x * 128;
  int cb = 0;
  if (MODE == 0) {
    cb = cnt[bz];
    if (i0 >= cb || n0 >= cb) return;
  } else {
    const int bb = i0 >> 10;
    if ((i0 & 1023) >= cnt[bb]) return;
  }
  const u16* Ab = A + (long)bz * sA;
  const u16* Bb = B + (long)bz * sB;
  const int wrow = (BM == 128) ? (w >> 1) * 64 : 0;
  const int wcol = (BM == 128) ? (w & 1) * 64 : w * 32;
  constexpr int NR = (BM == 128) ? 4 : 2;
  const int srow = t >> 2;         // 0..63 staging row
  const int scol = (t & 3) * 8;    // staging col (elems)
  const int rA = lane & 15, kb = (lane >> 4) * 8;
  f32x4 acc[4][NR] = {};

  for (int kt = 0; kt < K; kt += 32) {
    __syncthreads();
    async_lds16(Ab + (long)(i0 +      srow) * lda + kt + scol, &lA[       w*512]);
    if constexpr (BM == 128)
      async_lds16(Ab + (long)(i0 + 64 + srow) * lda + kt + scol, &lA[2048 + w*512]);
    async_lds16(Bb + (long)(n0 +      srow) * ldb + kt + scol, &lB[       w*512]);
    async_lds16(Bb + (long)(n0 + 64 + srow) * ldb + kt + scol, &lB[2048 + w*512]);
    __syncthreads();
    short8 af[4], bfr[NR];
#pragma unroll
    for (int m = 0; m < 4; m++)
      af[m] = *(const short8*)&lA[(wrow + m*16 + rA)*32 + kb];
#pragma unroll
    for (int n = 0; n < NR; n++)
      bfr[n] = *(const short8*)&lB[(wcol + n*16 + rA)*32 + kb];
#pragma unroll
    for (int m = 0; m < 4; m++)
#pragma unroll
      for (int n = 0; n < NR; n++)
        acc[m][n] = __builtin_amdgcn_mfma_f32_16x16x32_bf16(af[m], bfr[n], acc[m][n], 0, 0, 0);
  }

#pragma unroll
  for (int m = 0; m < 4; m++) {
    const int gi0 = i0 + wrow + m*16 + ((lane >> 4) << 2);
#pragma unroll
    for (int n = 0; n < NR; n++) {
      const int gj = n0 + wcol + n*16 + (lane & 15);
#pragma unroll
      for (int r = 0; r < 4; r++) {
        const int gi = gi0 + r;
        const float c = acc[m][n][r];
        if (MODE == 0) {
          if (gi < cb && gj < cb)
            ((unsigned char*)outp)[((long)bz << 20) + ((long)gi << 10) + gj] = (c > TAU_F) ? 1 : 0;
        } else if (MODE == 1) {
          const int b = gi >> 10, l = gi & 1023;
          ((u16*)outp)[(((long)(b*128 + gj)) << 10) + l] = f2bf(c);
        } else {
          ((u16*)outp)[(long)gi * 512 + gj] = f2bf(tanhf(c + bvec[gj]));
        }
      }
    }
  }
}

// ---------------- fused GAT attention, sparsity-skipping, compacted ----------
__global__ __launch_bounds__(256)
void gat_attn(const unsigned char* __restrict__ adj,
              const float* __restrict__ ald, const float* __restrict__ als,
              const u16* __restrict__ gT, const float* __restrict__ bias,
              const int* __restrict__ cnt,
              float* __restrict__ hf, u16* __restrict__ hall, int hall_off)
{
  __shared__ float red[4][16][132];
  __shared__ float ssumw[4][16];
  const int t = threadIdx.x, w = t >> 6, lane = t & 63;
  const int bz = blockIdx.y, i0 = blockIdx.x * 16;
  if (i0 >= cnt[bz]) return;
  const int rr = lane & 15, kg = lane >> 4;
  const int r0 = i0 + rr;
  const float ald0 = ald[(bz << 10) + r0];
  const unsigned char* arow = adj + ((long)bz << 20) + ((long)r0 << 10);
  const float* als_b = als + (bz << 10);
  const u16* gTb = gT + ((long)bz << 17);
  float s0 = 0.f;
  f32x4 acc[8] = {};
  const int jbase = w * 256 + kg * 8;

  u64 aw[8];
#pragma unroll
  for (int it = 0; it < 8; it++)
    aw[it] = *(const u64*)(arow + jbase + it*32);

#pragma unroll
  for (int it = 0; it < 8; it++) {
    const u64 a0 = aw[it];
    if (__any(a0 != 0ull)) {
      const int jl = jbase + it*32;
      const float4 f0 = *(const float4*)(als_b + jl);
      const float4 f1 = *(const float4*)(als_b + jl + 4);
      const float sv[8] = {f0.x, f0.y, f0.z, f0.w, f1.x, f1.y, f1.z, f1.w};
      short8 pa;
#pragma unroll
      for (int e = 0; e < 8; e++) {
        float x = ald0 + sv[e];
        x = x > 0.f ? x : 0.2f * x;
        const float p = ((a0 >> (8*e)) & 255ull) ? __expf(x) : 0.f;
        s0 += p;
        pa[e] = (short)f2bf(p);
      }
#pragma unroll
      for (int nf = 0; nf < 8; nf++) {
        const short8 b = *(const short8*)&gTb[(long)(nf*16 + rr) * 1024 + jl];
        acc[nf] = __builtin_amdgcn_mfma_f32_16x16x32_bf16(pa, b, acc[nf], 0, 0, 0);
      }
    }
  }

  s0 += __shfl_xor(s0, 16, 64);
  s0 += __shfl_xor(s0, 32, 64);
  if (lane < 16) ssumw[w][lane] = s0;
#pragma unroll
  for (int nf = 0; nf < 8; nf++)
#pragma unroll
    for (int rg = 0; rg < 4; rg++)
      red[w][kg*4 + rg][nf*16 + rr] = acc[nf][rg];
  __syncthreads();

  const int r = t >> 4, c0 = (t & 15) * 8;
  const float sm = ssumw[0][r] + ssumw[1][r] + ssumw[2][r] + ssumw[3][r];
  const float inv = sm > 0.f ? 1.f / sm : 0.f;
  const long gi = ((long)bz << 10) + i0 + r;
  float* hrow = hf + gi * 128;
  u16* orow = hall + gi * 1024 + hall_off;
#pragma unroll
  for (int q = 0; q < 8; q++) {
    const int c = c0 + q;
    float v = (red[0][r][c] + red[1][r][c] + red[2][r][c] + red[3][r][c]) * inv + bias[c];
    v = v > 0.f ? v : 0.f;
    hrow[c] = v;
    orow[c] = f2bf(v);
  }
}

// ---------------- small kernels ----------------
// gather valid rows, normalize, write compacted hnc (bf16) + hallc cols 0..767
__global__ __launch_bounds__(256)
void hn_kernel(const float* __restrict__ hidden, const int* __restrict__ cnt,
               const int* __restrict__ idx, u16* __restrict__ hnc, u16* __restrict__ hallc)
{
  const int gr = blockIdx.x * 4 + (threadIdx.x >> 6);
  const int b = gr >> 10, c = gr & 1023;
  const int lane = threadIdx.x & 63;
  if (c >= cnt[b]) return;
  const int l = idx[gr];
  const float* h = hidden + (long)((b << 10) + l) * 768;
  float x[12]; float ss = 0.f;
#pragma unroll
  for (int k = 0; k < 12; k++) { x[k] = h[k*64 + lane]; ss += x[k]*x[k]; }
#pragma unroll
  for (int o = 32; o > 0; o >>= 1) ss += __shfl_xor(ss, o, 64);
  const float inv = 1.f / fmaxf(sqrtf(ss), 1e-8f);
#pragma unroll
  for (int k = 0; k < 12; k++) {
    hnc[(long)gr*768   + k*64 + lane] = f2bf(x[k] * inv);
    hallc[(long)gr*1024 + k*64 + lane] = f2bf(x[k]);
  }
}

__global__ void transpose_bf(const float* __restrict__ in, u16* __restrict__ out, int K, int N)
{
  const int idx = blockIdx.x * 256 + threadIdx.x;
  if (idx >= K * N) return;
  const int k = idx / N, n = idx % N;
  out[(long)n * K + k] = f2bf(in[idx]);
}

__global__ void ae_kernel(const float* we0, const float* ao0, const float* we1, const float* ao1, float* out)
{
  __shared__ float s0[128], s1[128];
  const int t = threadIdx.x;
  s0[t] = we0[t] * ao0[t];
  s1[t] = we1[t] * ao1[t];
  __syncthreads();
  for (int o = 64; o > 0; o >>= 1) { if (t < o) { s0[t]+=s0[t+o]; s1[t]+=s1[t+o]; } __syncthreads(); }
  if (t == 0) { out[0] = s0[0]; out[1] = s1[0]; }
}

__global__ void al_kernel(const u16* __restrict__ gT,
                          const float* __restrict__ a_src, const float* __restrict__ a_dst,
                          const float* __restrict__ aeptr, const int* __restrict__ cnt,
                          float* __restrict__ als, float* __restrict__ ald)
{
  const int b = blockIdx.y;
  const int l = blockIdx.x * 256 + threadIdx.x;
  if (l >= cnt[b]) return;
  const u16* g = gT + ((long)b << 17) + l;
  float ss = 0.f, sd = 0.f;
#pragma unroll 4
  for (int c = 0; c < 128; c++) {
    const float v = bf2f(g[(long)c << 10]);
    ss += v * a_src[c];
    sd += v * a_dst[c];
  }
  als[(b << 10) + l] = ss;
  ald[(b << 10) + l] = sd + aeptr[0];
}

__global__ __launch_bounds__(256)
void gemv_scores(const u16* __restrict__ tb, const float* __restrict__ S2W,
                 const float* __restrict__ S2b, const int* __restrict__ cnt,
                 float* __restrict__ scores)
{
  const int row = blockIdx.x * 4 + (threadIdx.x >> 6);
  const int b = row >> 10, c = row & 1023;
  const int lane = threadIdx.x & 63;
  if (c >= cnt[b]) return;
  const short8 v = *(const short8*)&tb[(long)row * 512 + lane * 8];
  float s = 0.f;
#pragma unroll
  for (int i = 0; i < 8; i++) s += bf2f((u16)v[i]) * S2W[lane*8 + i];
#pragma unroll
  for (int o = 32; o > 0; o >>= 1) s += __shfl_xor(s, o, 64);
  if (lane == 0) scores[row] = s + S2b[0];
}

__global__ void softmax_w(const float* __restrict__ scores, const int* __restrict__ cnt,
                          float* __restrict__ wts)
{
  __shared__ float wsum[4];
  const int b = blockIdx.x, t = threadIdx.x;
  const int cb = cnt[b];
  float e[4]; float part = 0.f;
#pragma unroll
  for (int q = 0; q < 4; q++) {
    const int l = q*256 + t;
    const float ex = (l < cb) ? __expf(scores[(b<<10) + l]) : 0.f;
    e[q] = ex; part += ex;
  }
#pragma unroll
  for (int o = 32; o > 0; o >>= 1) part += __shfl_xor(part, o, 64);
  if ((t & 63) == 0) wsum[t >> 6] = part;
  __syncthreads();
  const float total = wsum[0] + wsum[1] + wsum[2] + wsum[3];
  const float inv = 1.f / fmaxf(total, 1e-16f);
#pragma unroll
  for (int q = 0; q < 4; q++) wts[(b<<10) + q*256 + t] = e[q] * inv;
}

__global__ void zero_out_k(float* out){ out[blockIdx.x*256 + threadIdx.x] = 0.f; }

__global__ __launch_bounds__(256)
void pooled_kernel(const float* __restrict__ hidden, const float* __restrict__ h1f,
                   const float* __restrict__ h2f, const float* __restrict__ wts,
                   const int* __restrict__ cnt, const int* __restrict__ idx,
                   float* __restrict__ out)
{
  const int b = blockIdx.y, l0 = blockIdx.x * 64, t = threadIdx.x;
  const int cb = cnt[b];
  if (l0 >= cb) return;
  const int lim = min(64, cb - l0);
  float a0=0.f, a1=0.f, a2=0.f, a3=0.f;
  for (int l = 0; l < lim; l++) {
    const int gl = (b << 10) + l0 + l;
    const float wv = wts[gl];
    const float* hr = hidden + (long)((b << 10) + idx[gl]) * 768;
    a0 += wv * hr[t];
    a1 += wv * hr[256 + t];
    a2 += wv * hr[512 + t];
    const float v3 = (t < 128) ? h1f[(long)gl*128 + t] : h2f[(long)gl*128 + (t - 128)];
    a3 += wv * v3;
  }
  atomicAdd(&out[(b<<10) + t],        a0);
  atomicAdd(&out[(b<<10) + 256 + t],  a1);
  atomicAdd(&out[(b<<10) + 512 + t],  a2);
  atomicAdd(&out[(b<<10) + 768 + t],  a3);
}

// ---------------- launch ----------------
extern "C" void kernel_launch(void* const* d_in, const int* in_sizes, int n_in,
                              void* d_out, int out_size, void* d_ws, size_t ws_size,
                              hipStream_t stream)
{
  const float* hidden = (const float*)d_in[0];
  const int*   mask   = (const int*)d_in[1];
  const float* W0     = (const float*)d_in[2];
  const float* asrc0  = (const float*)d_in[3];
  const float* adst0  = (const float*)d_in[4];
  const float* wed0   = (const float*)d_in[5];
  const float* aed0   = (const float*)d_in[6];
  const float* bias0  = (const float*)d_in[7];
  const float* W1     = (const float*)d_in[8];
  const float* asrc1  = (const float*)d_in[9];
  const float* adst1  = (const float*)d_in[10];
  const float* wed1   = (const float*)d_in[11];
  const float* aed1   = (const float*)d_in[12];
  const float* bias1  = (const float*)d_in[13];
  const float* S1W    = (const float*)d_in[14];
  const float* S1b    = (const float*)d_in[15];
  const float* S2W    = (const float*)d_in[16];
  const float* S2b    = (const float*)d_in[17];
  float* out = (float*)d_out;

  char* ws = (char*)d_ws;
  u16* hallc = (u16*)(ws + 0);                    // 16384x1024 bf16 compacted (33554432 B)
  u16* hnc  = (u16*)(ws + 33554432);              // 16384x768 bf16 compacted (25165824 B), reused as tb
  u16* tb   = hnc;                                // tanh buf 16384x512 bf16 (16 MB), written after hnc last read
  unsigned char* adj = (unsigned char*)(ws + 58720256); // 16x1024x1024 (16777216 B)
  u16* gt   = (u16*)(ws + 75497472);              // 16x128x1024 bf16 (4194304 B)
  u16* w0t  = (u16*)(ws + 79691776);              // 128x768
  u16* w1t  = (u16*)(ws + 79888384);              // 128x128
  u16* s1t  = (u16*)(ws + 79921152);              // 512x1024
  float* ald = (float*)(ws + 80969728);           // 16x1024
  float* als = (float*)(ws + 81035264);           // 16x1024
  float* h1f = (float*)(ws + 81100800);           // 16x1024x128 f32 compacted
  float* h2f = (float*)(ws + 89489408);           // 16x1024x128 f32 compacted
  float* scores = (float*)(ws + 97878016);        // 16x1024
  float* wts    = (float*)(ws + 97943552);        // 16x1024
  float* aeb    = (float*)(ws + 98009088);        // 2 floats
  int*   cnt    = (int*)(ws + 98009600);          // 16 ints
  int*   idxb   = (int*)(ws + 98010112);          // 16x1024 ints (65536 B)

  hipMemsetAsync(adj, 0, 16u*1024*1024, stream);  // pad region of adj must be 0 every call
  zero_out_k<<<64, 256, 0, stream>>>(out);
  ae_kernel<<<1, 128, 0, stream>>>(wed0, aed0, wed1, aed1, aeb);
  compact_kernel<<<16, 1024, 0, stream>>>(mask, cnt, idxb);
  transpose_bf<<<384,  256, 0, stream>>>(W0,  w0t, 768, 128);
  transpose_bf<<<64,   256, 0, stream>>>(W1,  w1t, 128, 128);
  transpose_bf<<<2048, 256, 0, stream>>>(S1W, s1t, 1024, 512);
  hn_kernel<<<4096, 256, 0, stream>>>(hidden, cnt, idxb, hnc, hallc);

  // adjacency in compacted space: sim > TAU on valid-node pairs
  gemm_nt<0,128><<<dim3(8,8,16), 256, 0, stream>>>(hnc, hnc, 768, 768, 768,
        (long)1024*768, (long)1024*768, adj, cnt, nullptr);

  // layer 0
  gemm_nt<1,64><<<dim3(1,256,1), 256, 0, stream>>>(hallc, w0t, 1024, 768, 768, 0, 0, gt, cnt, nullptr);
  al_kernel<<<dim3(4,16), 256, 0, stream>>>(gt, asrc0, adst0, aeb, cnt, als, ald);
  gat_attn<<<dim3(64,16), 256, 0, stream>>>(adj, ald, als, gt, bias0, cnt, h1f, hallc, 768);

  // layer 1
  gemm_nt<1,64><<<dim3(1,256,1), 256, 0, stream>>>(hallc + 768, w1t, 1024, 128, 128, 0, 0, gt, cnt, nullptr);
  al_kernel<<<dim3(4,16), 256, 0, stream>>>(gt, asrc1, adst1, aeb + 1, cnt, als, ald);
  gat_attn<<<dim3(64,16), 256, 0, stream>>>(adj, ald, als, gt, bias1, cnt, h2f, hallc, 896);

  // scorer
  gemm_nt<2,128><<<dim3(4,128,1), 256, 0, stream>>>(hallc, s1t, 1024, 1024, 1024, 0, 0, tb, cnt, S1b);
  gemv_scores<<<4096, 256, 0, stream>>>(tb, S2W, S2b, cnt, scores);
  softmax_w<<<16, 256, 0, stream>>>(scores, cnt, wts);
  pooled_kernel<<<dim3(16,16), 256, 0, stream>>>(hidden, h1f, h2f, wts, cnt, idxb, out);
}

// Round 5
// 179.307 us; speedup vs baseline: 1.9446x; 1.1308x over previous
//
#include <hip/hip_runtime.h>

typedef __attribute__((ext_vector_type(8))) short short8;
typedef __attribute__((ext_vector_type(4))) float f32x4;
typedef unsigned short u16;
typedef unsigned int u32;
typedef unsigned long long u64;

#define TAU_F 0.3f

__device__ __forceinline__ u16 f2bf(float f){
  u32 u = __float_as_uint(f);
  u32 r = u + 0x7FFFu + ((u >> 16) & 1u);
  return (u16)(r >> 16);
}
__device__ __forceinline__ float bf2f(u16 v){
  return __uint_as_float(((u32)v) << 16);
}

typedef __attribute__((address_space(1))) const u32 glb_u32;
typedef __attribute__((address_space(3))) u32 lds_u32;
__device__ __forceinline__ void async_lds16(const void* g, void* l){
  __builtin_amdgcn_global_load_lds((glb_u32*)g, (lds_u32*)l, 16, 0, 0);
}

// ---------------- compaction: per-batch valid-node count + index list --------
__global__ __launch_bounds__(1024)
void compact_kernel(const int* __restrict__ mask, int* __restrict__ cnt, int* __restrict__ idx)
{
  __shared__ int wtot[16];
  __shared__ int woff[16];
  const int b = blockIdx.x, t = threadIdx.x;
  const int w = t >> 6, lane = t & 63;
  const int m = mask[(b << 10) + t];
  const u64 bal = __ballot(m != 0);
  const int pos = __popcll(bal & ((1ull << lane) - 1ull));
  if (lane == 0) wtot[w] = __popcll(bal);
  __syncthreads();
  if (t == 0) {
    int acc = 0;
    for (int i = 0; i < 16; i++) { woff[i] = acc; acc += wtot[i]; }
    cnt[b] = acc;
  }
  __syncthreads();
  if (m) idx[(b << 10) + woff[w] + pos] = t;
}

// ------- bf16 NT GEMM, 64x64 tile, BK=64, double-buffered, XOR-swizzled -------
// MODE 0: adj-byte epilogue (sim > TAU, guarded to [0,cnt)^2; pad pre-zeroed)
// MODE 1: gT store  (out[(b*128+c)*1024 + l] = bf16(acc)), b=row>>10, l=row&1023
// MODE 2: tanh(acc + bvec[col]) -> bf16, ldc=512
template<int MODE>
__global__ __launch_bounds__(256)
void gemm_nt(const u16* __restrict__ A, const u16* __restrict__ B,
             int lda, int ldb, int K, long sA, long sB,
             void* __restrict__ outp,
             const int* __restrict__ cnt,
             const float* __restrict__ bvec)
{
  __shared__ u16 lA[2][64*64];
  __shared__ u16 lB[2][64*64];
  const int t = threadIdx.x;
  const int w = t >> 6, lane = t & 63;
  const int bz = blockIdx.z;
  const int i0 = blockIdx.y * 64, n0 = blockIdx.x * 64;
  int cb = 0;
  if (MODE == 0) {
    cb = cnt[bz];
    if (i0 >= cb || n0 >= cb) return;
  } else {
    if ((i0 & 1023) >= cnt[i0 >> 10]) return;
  }
  const u16* Ab = A + (long)bz * sA;
  const u16* Bb = B + (long)bz * sB;
  const int wr = w >> 1, wc = w & 1;
  // staging: thread t covers rows (t>>3) and (t>>3)+32, col-group t&7 (8 elems)
  const int srow = t >> 3, scg = t & 7;
  const int sc0 = ((scg ^ (srow & 7)) << 3);      // swizzled source col offset
  const long arow0 = (long)(i0 + srow) * lda, arow1 = (long)(i0 + srow + 32) * lda;
  const long brow0 = (long)(n0 + srow) * ldb, brow1 = (long)(n0 + srow + 32) * ldb;
  // fragment read offsets (swizzle-aware)
  const int rA = lane & 15, kg = lane >> 4;
  const int sw = rA & 7;
  const int off0 = ((kg ^ sw) << 3);              // kk = 0
  const int off1 = (((4 + kg) ^ sw) << 3);        // kk = 1
  const int rowA0 = (wr*32 + rA) * 64, rowA1 = (wr*32 + 16 + rA) * 64;
  const int rowB0 = (wc*32 + rA) * 64, rowB1 = (wc*32 + 16 + rA) * 64;
  f32x4 acc[2][2] = {};

  auto stage = [&](int buf, int kt) {
    async_lds16(Ab + arow0 + kt + sc0, &lA[buf][t*8]);
    async_lds16(Ab + arow1 + kt + sc0, &lA[buf][2048 + t*8]);
    async_lds16(Bb + brow0 + kt + sc0, &lB[buf][t*8]);
    async_lds16(Bb + brow1 + kt + sc0, &lB[buf][2048 + t*8]);
  };
  auto compute = [&](int buf) {
    short8 a00 = *(const short8*)&lA[buf][rowA0 + off0];
    short8 a01 = *(const short8*)&lA[buf][rowA0 + off1];
    short8 a10 = *(const short8*)&lA[buf][rowA1 + off0];
    short8 a11 = *(const short8*)&lA[buf][rowA1 + off1];
    short8 b00 = *(const short8*)&lB[buf][rowB0 + off0];
    short8 b01 = *(const short8*)&lB[buf][rowB0 + off1];
    short8 b10 = *(const short8*)&lB[buf][rowB1 + off0];
    short8 b11 = *(const short8*)&lB[buf][rowB1 + off1];
    acc[0][0] = __builtin_amdgcn_mfma_f32_16x16x32_bf16(a00, b00, acc[0][0], 0, 0, 0);
    acc[0][1] = __builtin_amdgcn_mfma_f32_16x16x32_bf16(a00, b10, acc[0][1], 0, 0, 0);
    acc[1][0] = __builtin_amdgcn_mfma_f32_16x16x32_bf16(a10, b00, acc[1][0], 0, 0, 0);
    acc[1][1] = __builtin_amdgcn_mfma_f32_16x16x32_bf16(a10, b10, acc[1][1], 0, 0, 0);
    acc[0][0] = __builtin_amdgcn_mfma_f32_16x16x32_bf16(a01, b01, acc[0][0], 0, 0, 0);
    acc[0][1] = __builtin_amdgcn_mfma_f32_16x16x32_bf16(a01, b11, acc[0][1], 0, 0, 0);
    acc[1][0] = __builtin_amdgcn_mfma_f32_16x16x32_bf16(a11, b01, acc[1][0], 0, 0, 0);
    acc[1][1] = __builtin_amdgcn_mfma_f32_16x16x32_bf16(a11, b11, acc[1][1], 0, 0, 0);
  };

  const int nt = K >> 6;
  stage(0, 0);
  __syncthreads();
  int cur = 0;
  for (int kt = 1; kt < nt; kt++) {
    stage(cur ^ 1, kt << 6);
    compute(cur);
    __syncthreads();
    cur ^= 1;
  }
  compute(cur);

#pragma unroll
  for (int m = 0; m < 2; m++) {
    const int gi0 = i0 + wr*32 + m*16 + kg*4;
#pragma unroll
    for (int n = 0; n < 2; n++) {
      const int gj = n0 + wc*32 + n*16 + rA;
#pragma unroll
      for (int r = 0; r < 4; r++) {
        const int gi = gi0 + r;
        const float c = acc[m][n][r];
        if (MODE == 0) {
          if (gi < cb && gj < cb)
            ((unsigned char*)outp)[((long)bz << 20) + ((long)gi << 10) + gj] = (c > TAU_F) ? 1 : 0;
        } else if (MODE == 1) {
          const int b = gi >> 10, l = gi & 1023;
          ((u16*)outp)[(((long)(b*128 + gj)) << 10) + l] = f2bf(c);
        } else {
          ((u16*)outp)[(long)gi * 512 + gj] = f2bf(tanhf(c + bvec[gj]));
        }
      }
    }
  }
}

// ---------------- fused GAT attention, sparsity-skipping, compacted ----------
__global__ __launch_bounds__(256)
void gat_attn(const unsigned char* __restrict__ adj,
              const float* __restrict__ ald, const float* __restrict__ als,
              const u16* __restrict__ gT, const float* __restrict__ bias,
              const int* __restrict__ cnt,
              float* __restrict__ hf, u16* __restrict__ hall, int hall_off)
{
  __shared__ float red[4][16][132];
  __shared__ float ssumw[4][16];
  const int t = threadIdx.x, w = t >> 6, lane = t & 63;
  const int bz = blockIdx.y, i0 = blockIdx.x * 16;
  if (i0 >= cnt[bz]) return;
  const int rr = lane & 15, kg = lane >> 4;
  const int r0 = i0 + rr;
  const float ald0 = ald[(bz << 10) + r0];
  const unsigned char* arow = adj + ((long)bz << 20) + ((long)r0 << 10);
  const float* als_b = als + (bz << 10);
  const u16* gTb = gT + ((long)bz << 17);
  float s0 = 0.f;
  f32x4 acc[8] = {};
  const int jbase = w * 256 + kg * 8;

  u64 aw[8];
#pragma unroll
  for (int it = 0; it < 8; it++)
    aw[it] = *(const u64*)(arow + jbase + it*32);

#pragma unroll
  for (int it = 0; it < 8; it++) {
    const u64 a0 = aw[it];
    if (__any(a0 != 0ull)) {
      const int jl = jbase + it*32;
      const float4 f0 = *(const float4*)(als_b + jl);
      const float4 f1 = *(const float4*)(als_b + jl + 4);
      const float sv[8] = {f0.x, f0.y, f0.z, f0.w, f1.x, f1.y, f1.z, f1.w};
      short8 pa;
#pragma unroll
      for (int e = 0; e < 8; e++) {
        float x = ald0 + sv[e];
        x = x > 0.f ? x : 0.2f * x;
        const float p = ((a0 >> (8*e)) & 255ull) ? __expf(x) : 0.f;
        s0 += p;
        pa[e] = (short)f2bf(p);
      }
#pragma unroll
      for (int nf = 0; nf < 8; nf++) {
        const short8 b = *(const short8*)&gTb[(long)(nf*16 + rr) * 1024 + jl];
        acc[nf] = __builtin_amdgcn_mfma_f32_16x16x32_bf16(pa, b, acc[nf], 0, 0, 0);
      }
    }
  }

  s0 += __shfl_xor(s0, 16, 64);
  s0 += __shfl_xor(s0, 32, 64);
  if (lane < 16) ssumw[w][lane] = s0;
#pragma unroll
  for (int nf = 0; nf < 8; nf++)
#pragma unroll
    for (int rg = 0; rg < 4; rg++)
      red[w][kg*4 + rg][nf*16 + rr] = acc[nf][rg];
  __syncthreads();

  const int r = t >> 4, c0 = (t & 15) * 8;
  const float sm = ssumw[0][r] + ssumw[1][r] + ssumw[2][r] + ssumw[3][r];
  const float inv = sm > 0.f ? 1.f / sm : 0.f;
  const long gi = ((long)bz << 10) + i0 + r;
  float* hrow = hf + gi * 128;
  u16* orow = hall + gi * 1024 + hall_off;
#pragma unroll
  for (int q = 0; q < 8; q++) {
    const int c = c0 + q;
    float v = (red[0][r][c] + red[1][r][c] + red[2][r][c] + red[3][r][c]) * inv + bias[c];
    v = v > 0.f ? v : 0.f;
    hrow[c] = v;
    orow[c] = f2bf(v);
  }
}

// ---------------- small kernels ----------------
__global__ __launch_bounds__(256)
void hn_kernel(const float* __restrict__ hidden, const int* __restrict__ cnt,
               const int* __restrict__ idx, u16* __restrict__ hnc, u16* __restrict__ hallc)
{
  const int gr = blockIdx.x * 4 + (threadIdx.x >> 6);
  const int b = gr >> 10, c = gr & 1023;
  const int lane = threadIdx.x & 63;
  if (c >= cnt[b]) return;
  const int l = idx[gr];
  const float* h = hidden + (long)((b << 10) + l) * 768;
  float x[12]; float ss = 0.f;
#pragma unroll
  for (int k = 0; k < 12; k++) { x[k] = h[k*64 + lane]; ss += x[k]*x[k]; }
#pragma unroll
  for (int o = 32; o > 0; o >>= 1) ss += __shfl_xor(ss, o, 64);
  const float inv = 1.f / fmaxf(sqrtf(ss), 1e-8f);
#pragma unroll
  for (int k = 0; k < 12; k++) {
    hnc[(long)gr*768   + k*64 + lane] = f2bf(x[k] * inv);
    hallc[(long)gr*1024 + k*64 + lane] = f2bf(x[k]);
  }
}

__global__ void transpose_bf(const float* __restrict__ in, u16* __restrict__ out, int K, int N)
{
  const int idx = blockIdx.x * 256 + threadIdx.x;
  if (idx >= K * N) return;
  const int k = idx / N, n = idx % N;
  out[(long)n * K + k] = f2bf(in[idx]);
}

__global__ void ae_kernel(const float* we0, const float* ao0, const float* we1, const float* ao1, float* out)
{
  __shared__ float s0[128], s1[128];
  const int t = threadIdx.x;
  s0[t] = we0[t] * ao0[t];
  s1[t] = we1[t] * ao1[t];
  __syncthreads();
  for (int o = 64; o > 0; o >>= 1) { if (t < o) { s0[t]+=s0[t+o]; s1[t]+=s1[t+o]; } __syncthreads(); }
  if (t == 0) { out[0] = s0[0]; out[1] = s1[0]; }
}

__global__ void al_kernel(const u16* __restrict__ gT,
                          const float* __restrict__ a_src, const float* __restrict__ a_dst,
                          const float* __restrict__ aeptr, const int* __restrict__ cnt,
                          float* __restrict__ als, float* __restrict__ ald)
{
  const int b = blockIdx.y;
  const int l = blockIdx.x * 256 + threadIdx.x;
  if (l >= cnt[b]) return;
  const u16* g = gT + ((long)b << 17) + l;
  float ss = 0.f, sd = 0.f;
#pragma unroll 4
  for (int c = 0; c < 128; c++) {
    const float v = bf2f(g[(long)c << 10]);
    ss += v * a_src[c];
    sd += v * a_dst[c];
  }
  als[(b << 10) + l] = ss;
  ald[(b << 10) + l] = sd + aeptr[0];
}

__global__ __launch_bounds__(256)
void gemv_scores(const u16* __restrict__ tb, const float* __restrict__ S2W,
                 const float* __restrict__ S2b, const int* __restrict__ cnt,
                 float* __restrict__ scores)
{
  const int row = blockIdx.x * 4 + (threadIdx.x >> 6);
  const int b = row >> 10, c = row & 1023;
  const int lane = threadIdx.x & 63;
  if (c >= cnt[b]) return;
  const short8 v = *(const short8*)&tb[(long)row * 512 + lane * 8];
  float s = 0.f;
#pragma unroll
  for (int i = 0; i < 8; i++) s += bf2f((u16)v[i]) * S2W[lane*8 + i];
#pragma unroll
  for (int o = 32; o > 0; o >>= 1) s += __shfl_xor(s, o, 64);
  if (lane == 0) scores[row] = s + S2b[0];
}

__global__ void softmax_w(const float* __restrict__ scores, const int* __restrict__ cnt,
                          float* __restrict__ wts)
{
  __shared__ float wsum[4];
  const int b = blockIdx.x, t = threadIdx.x;
  const int cb = cnt[b];
  float e[4]; float part = 0.f;
#pragma unroll
  for (int q = 0; q < 4; q++) {
    const int l = q*256 + t;
    const float ex = (l < cb) ? __expf(scores[(b<<10) + l]) : 0.f;
    e[q] = ex; part += ex;
  }
#pragma unroll
  for (int o = 32; o > 0; o >>= 1) part += __shfl_xor(part, o, 64);
  if ((t & 63) == 0) wsum[t >> 6] = part;
  __syncthreads();
  const float total = wsum[0] + wsum[1] + wsum[2] + wsum[3];
  const float inv = 1.f / fmaxf(total, 1e-16f);
#pragma unroll
  for (int q = 0; q < 4; q++) wts[(b<<10) + q*256 + t] = e[q] * inv;
}

__global__ void zero_out_k(float* out){ out[blockIdx.x*256 + threadIdx.x] = 0.f; }

__global__ __launch_bounds__(256)
void pooled_kernel(const float* __restrict__ hidden, const float* __restrict__ h1f,
                   const float* __restrict__ h2f, const float* __restrict__ wts,
                   const int* __restrict__ cnt, const int* __restrict__ idx,
                   float* __restrict__ out)
{
  const int b = blockIdx.y, l0 = blockIdx.x * 64, t = threadIdx.x;
  const int cb = cnt[b];
  if (l0 >= cb) return;
  const int lim = min(64, cb - l0);
  float a0=0.f, a1=0.f, a2=0.f, a3=0.f;
  for (int l = 0; l < lim; l++) {
    const int gl = (b << 10) + l0 + l;
    const float wv = wts[gl];
    const float* hr = hidden + (long)((b << 10) + idx[gl]) * 768;
    a0 += wv * hr[t];
    a1 += wv * hr[256 + t];
    a2 += wv * hr[512 + t];
    const float v3 = (t < 128) ? h1f[(long)gl*128 + t] : h2f[(long)gl*128 + (t - 128)];
    a3 += wv * v3;
  }
  atomicAdd(&out[(b<<10) + t],        a0);
  atomicAdd(&out[(b<<10) + 256 + t],  a1);
  atomicAdd(&out[(b<<10) + 512 + t],  a2);
  atomicAdd(&out[(b<<10) + 768 + t],  a3);
}

// ---------------- launch ----------------
extern "C" void kernel_launch(void* const* d_in, const int* in_sizes, int n_in,
                              void* d_out, int out_size, void* d_ws, size_t ws_size,
                              hipStream_t stream)
{
  const float* hidden = (const float*)d_in[0];
  const int*   mask   = (const int*)d_in[1];
  const float* W0     = (const float*)d_in[2];
  const float* asrc0  = (const float*)d_in[3];
  const float* adst0  = (const float*)d_in[4];
  const float* wed0   = (const float*)d_in[5];
  const float* aed0   = (const float*)d_in[6];
  const float* bias0  = (const float*)d_in[7];
  const float* W1     = (const float*)d_in[8];
  const float* asrc1  = (const float*)d_in[9];
  const float* adst1  = (const float*)d_in[10];
  const float* wed1   = (const float*)d_in[11];
  const float* aed1   = (const float*)d_in[12];
  const float* bias1  = (const float*)d_in[13];
  const float* S1W    = (const float*)d_in[14];
  const float* S1b    = (const float*)d_in[15];
  const float* S2W    = (const float*)d_in[16];
  const float* S2b    = (const float*)d_in[17];
  float* out = (float*)d_out;

  char* ws = (char*)d_ws;
  u16* hallc = (u16*)(ws + 0);                    // 16384x1024 bf16 compacted (33554432 B)
  u16* hnc  = (u16*)(ws + 33554432);              // 16384x768 bf16 compacted (25165824 B), reused as tb
  u16* tb   = hnc;                                // tanh buf 16384x512 bf16 (16 MB), written after hnc last read
  unsigned char* adj = (unsigned char*)(ws + 58720256); // 16x1024x1024 (16777216 B)
  u16* gt   = (u16*)(ws + 75497472);              // 16x128x1024 bf16 (4194304 B)
  u16* w0t  = (u16*)(ws + 79691776);              // 128x768
  u16* w1t  = (u16*)(ws + 79888384);              // 128x128
  u16* s1t  = (u16*)(ws + 79921152);              // 512x1024
  float* ald = (float*)(ws + 80969728);           // 16x1024
  float* als = (float*)(ws + 81035264);           // 16x1024
  float* h1f = (float*)(ws + 81100800);           // 16x1024x128 f32 compacted
  float* h2f = (float*)(ws + 89489408);           // 16x1024x128 f32 compacted
  float* scores = (float*)(ws + 97878016);        // 16x1024
  float* wts    = (float*)(ws + 97943552);        // 16x1024
  float* aeb    = (float*)(ws + 98009088);        // 2 floats
  int*   cnt    = (int*)(ws + 98009600);          // 16 ints
  int*   idxb   = (int*)(ws + 98010112);          // 16x1024 ints (65536 B)

  hipMemsetAsync(adj, 0, 16u*1024*1024, stream);  // pad region of adj must be 0 every call
  zero_out_k<<<64, 256, 0, stream>>>(out);
  ae_kernel<<<1, 128, 0, stream>>>(wed0, aed0, wed1, aed1, aeb);
  compact_kernel<<<16, 1024, 0, stream>>>(mask, cnt, idxb);
  transpose_bf<<<384,  256, 0, stream>>>(W0,  w0t, 768, 128);
  transpose_bf<<<64,   256, 0, stream>>>(W1,  w1t, 128, 128);
  transpose_bf<<<2048, 256, 0, stream>>>(S1W, s1t, 1024, 512);
  hn_kernel<<<4096, 256, 0, stream>>>(hidden, cnt, idxb, hnc, hallc);

  // adjacency in compacted space: sim > TAU on valid-node pairs
  gemm_nt<0><<<dim3(16,16,16), 256, 0, stream>>>(hnc, hnc, 768, 768, 768,
        (long)1024*768, (long)1024*768, adj, cnt, nullptr);

  // layer 0
  gemm_nt<1><<<dim3(2,256,1), 256, 0, stream>>>(hallc, w0t, 1024, 768, 768, 0, 0, gt, cnt, nullptr);
  al_kernel<<<dim3(4,16), 256, 0, stream>>>(gt, asrc0, adst0, aeb, cnt, als, ald);
  gat_attn<<<dim3(64,16), 256, 0, stream>>>(adj, ald, als, gt, bias0, cnt, h1f, hallc, 768);

  // layer 1
  gemm_nt<1><<<dim3(2,256,1), 256, 0, stream>>>(hallc + 768, w1t, 1024, 128, 128, 0, 0, gt, cnt, nullptr);
  al_kernel<<<dim3(4,16), 256, 0, stream>>>(gt, asrc1, adst1, aeb + 1, cnt, als, ald);
  gat_attn<<<dim3(64,16), 256, 0, stream>>>(adj, ald, als, gt, bias1, cnt, h2f, hallc, 896);

  // scorer
  gemm_nt<2><<<dim3(8,256,1), 256, 0, stream>>>(hallc, s1t, 1024, 1024, 1024, 0, 0, tb, cnt, S1b);
  gemv_scores<<<4096, 256, 0, stream>>>(tb, S2W, S2b, cnt, scores);
  softmax_w<<<16, 256, 0, stream>>>(scores, cnt, wts);
  pooled_kernel<<<dim3(16,16), 256, 0, stream>>>(hidden, h1f, h2f, wts, cnt, idxb, out);
}